// Round 4
// baseline (1010.646 us; speedup 1.0000x reference)
//
#include <hip/hip_runtime.h>

typedef unsigned short u16;
typedef __attribute__((ext_vector_type(8))) short short8;
typedef __attribute__((ext_vector_type(4))) float floatx4;
typedef __attribute__((ext_vector_type(4))) unsigned int uintx4;

#define B_    16
#define C_    512
#define N_    4096
#define NH_   8
#define HD_   64
#define MQKV  1536

union V16 { uintx4 u; u16 s[8]; short8 h; };

__device__ inline float bf2f(u16 v) {
  union { unsigned int i; float f; } c; c.i = ((unsigned int)v) << 16; return c.f;
}
__device__ inline u16 f2bf(float f) {
  union { float f; unsigned int i; } c; c.f = f;
  unsigned int i = c.i;
  return (u16)((i + 0x7FFFu + ((i >> 16) & 1u)) >> 16);
}

// ---------------- Kernel 1: GroupNorm stats -> per-(b,c) affine (f32 in) ----------------
__global__ __launch_bounds__(256) void gn_stats(const float* __restrict__ x,
    const float* __restrict__ gamma, const float* __restrict__ beta,
    float* __restrict__ s_arr, float* __restrict__ t_arr) {
  int b = blockIdx.x >> 5, g = blockIdx.x & 31;
  const floatx4* p = (const floatx4*)(x + (size_t)(b * C_ + g * 16) * N_);
  int tid = threadIdx.x;
  float sum = 0.f, ssq = 0.f;
  for (int it = 0; it < 64; ++it) {
    floatx4 v = p[tid + it * 256];
#pragma unroll
    for (int j = 0; j < 4; ++j) { float f = v[j]; sum += f; ssq += f * f; }
  }
#pragma unroll
  for (int off = 32; off > 0; off >>= 1) {
    sum += __shfl_down(sum, off);
    ssq += __shfl_down(ssq, off);
  }
  __shared__ float red[8];
  __shared__ float mv[2];
  int lane = tid & 63, wid = tid >> 6;
  if (lane == 0) { red[wid] = sum; red[wid + 4] = ssq; }
  __syncthreads();
  if (tid == 0) {
    float s = red[0] + red[1] + red[2] + red[3];
    float q = red[4] + red[5] + red[6] + red[7];
    float mean = s * (1.f / 65536.f);
    float var  = q * (1.f / 65536.f) - mean * mean;
    mv[0] = mean; mv[1] = rsqrtf(var + 1e-5f);
  }
  __syncthreads();
  if (tid < 16) {
    int c = g * 16 + tid;
    float ga = gamma[c], be = beta[c];
    float mean = mv[0], rstd = mv[1];
    s_arr[b * C_ + c] = ga * rstd;
    t_arr[b * C_ + c] = be - mean * rstd * ga;
  }
}

// ------- Kernel 2/5: GEMM out[bz,o,n] = sum_c W[o,c] * affine(X[bz,c,n]) (+bias, +resid) ---
// W,bias,resid: f32. X: f32 (xIsF32=1) or bf16 (xIsF32=0). out: f32 (outF32=1) or bf16.
__global__ __launch_bounds__(256) void gemm_fused(
    const float* __restrict__ W,     // [M][512] f32
    const void* __restrict__ Xv,
    const float* __restrict__ bias,  // [M] f32
    const float* __restrict__ s_arr, const float* __restrict__ t_arr,
    const float* __restrict__ resid, // f32 or null
    void* __restrict__ outv,
    int M, int doGN, int doRes, int xIsF32, int outF32, size_t xbstride, int b0) {
  __shared__ u16 As[128 * 72];
  __shared__ u16 Bs[128 * 72];
  int bz = blockIdx.z;
  int gb = b0 + bz;
  int m0 = blockIdx.y * 128, n0 = blockIdx.x * 128;
  int tid = threadIdx.x, lane = tid & 63, wid = tid >> 6;
  int quad = lane >> 4, l15 = lane & 15;
  int wm = (wid >> 1) * 64, wn = (wid & 1) * 64;
  floatx4 acc[4][4];
#pragma unroll
  for (int i = 0; i < 4; ++i)
#pragma unroll
    for (int j = 0; j < 4; ++j) acc[i][j] = (floatx4)0.f;

  const size_t xbase = (size_t)bz * xbstride;
  for (int kt = 0; kt < 8; ++kt) {
    // stage A tile [128 m][64 k] from f32 W, convert to bf16
#pragma unroll
    for (int i = 0; i < 8; ++i) {
      int l = tid + i * 256;
      int row = l >> 4, c4 = (l & 15) * 4;
      floatx4 v = *(const floatx4*)(W + (size_t)(m0 + row) * 512 + kt * 64 + c4);
#pragma unroll
      for (int j = 0; j < 4; ++j) As[row * 72 + c4 + j] = f2bf(v[j]);
    }
    // stage B tile transposed: Bs[n][c], XOR swizzle on 8-chunks
    if (xIsF32) {
      const float* Xf = (const float*)Xv;
#pragma unroll
      for (int i = 0; i < 8; ++i) {
        int l = tid + i * 256;
        int ch = l >> 5, n4 = (l & 31) * 4;
        int c = kt * 64 + ch;
        floatx4 v = *(const floatx4*)(Xf + xbase + (size_t)c * N_ + n0 + n4);
        float s = 1.f, t = 0.f;
        if (doGN) { s = s_arr[gb * C_ + c]; t = t_arr[gb * C_ + c]; }
        int chunk = ch >> 3, clo = ch & 7;
#pragma unroll
        for (int j = 0; j < 4; ++j) {
          int nl = n4 + j;
          Bs[nl * 72 + ((chunk ^ ((nl >> 3) & 7)) * 8 + clo)] = f2bf(s * v[j] + t);
        }
      }
    } else {
      const u16* Xh = (const u16*)Xv;
#pragma unroll
      for (int i = 0; i < 4; ++i) {
        int l = tid + i * 256;
        int ch = l >> 4, n8 = (l & 15) * 8;
        int c = kt * 64 + ch;
        V16 v; v.u = *(const uintx4*)(Xh + xbase + (size_t)c * N_ + n0 + n8);
        int chunk = ch >> 3, clo = ch & 7;
#pragma unroll
        for (int j = 0; j < 8; ++j) {
          int nl = n8 + j;
          Bs[nl * 72 + ((chunk ^ ((nl >> 3) & 7)) * 8 + clo)] = v.s[j];
        }
      }
    }
    __syncthreads();
#pragma unroll
    for (int ks = 0; ks < 2; ++ks) {
      short8 af[4], bf8[4];
      int ko = ks * 32 + quad * 8;
#pragma unroll
      for (int mi = 0; mi < 4; ++mi)
        af[mi] = *(const short8*)&As[(wm + mi * 16 + l15) * 72 + ko];
      int chunk = ks * 4 + quad;
#pragma unroll
      for (int ni = 0; ni < 4; ++ni) {
        int nl = wn + ni * 16 + l15;
        bf8[ni] = *(const short8*)&Bs[nl * 72 + (chunk ^ ((nl >> 3) & 7)) * 8];
      }
#pragma unroll
      for (int mi = 0; mi < 4; ++mi)
#pragma unroll
        for (int ni = 0; ni < 4; ++ni)
          acc[mi][ni] = __builtin_amdgcn_mfma_f32_16x16x32_bf16(af[mi], bf8[ni], acc[mi][ni], 0, 0, 0);
    }
    __syncthreads();
  }
  // epilogue
#pragma unroll
  for (int mi = 0; mi < 4; ++mi) {
#pragma unroll
    for (int ni = 0; ni < 4; ++ni) {
#pragma unroll
      for (int r = 0; r < 4; ++r) {
        int o = m0 + wm + mi * 16 + quad * 4 + r;
        int n = n0 + wn + ni * 16 + l15;
        float vv = acc[mi][ni][r] + bias[o];
        size_t oidx = ((size_t)bz * M + o) * N_ + n;
        if (doRes) vv += resid[oidx];
        if (outF32) ((float*)outv)[oidx] = vv;
        else        ((u16*)outv)[oidx]   = f2bf(vv);
      }
    }
  }
}

// ---------------- Kernel 3: S = q k^T (over N), softmax rows -> attn f32 ----------------
__global__ __launch_bounds__(256) void qk_softmax(const u16* __restrict__ qkv,
                                                  float* __restrict__ attn) {
  int h = blockIdx.x, bz = blockIdx.y;
  const u16* qb = qkv + ((size_t)bz * MQKV + h * HD_) * N_;
  const u16* kb = qkv + ((size_t)bz * MQKV + C_ + h * HD_) * N_;
  int tid = threadIdx.x, lane = tid & 63, wid = tid >> 6;
  int quad = lane >> 4, l15 = lane & 15;
  floatx4 acc[4][4];
#pragma unroll
  for (int i = 0; i < 4; ++i)
#pragma unroll
    for (int j = 0; j < 4; ++j) acc[i][j] = (floatx4)0.f;

  for (int ks = 0; ks < 32; ++ks) {
    int n = wid * 1024 + ks * 32 + quad * 8;
    short8 af[4], bf8[4];
#pragma unroll
    for (int mi = 0; mi < 4; ++mi)
      af[mi] = *(const short8*)(qb + (size_t)(mi * 16 + l15) * N_ + n);
#pragma unroll
    for (int ni = 0; ni < 4; ++ni)
      bf8[ni] = *(const short8*)(kb + (size_t)(ni * 16 + l15) * N_ + n);
#pragma unroll
    for (int mi = 0; mi < 4; ++mi)
#pragma unroll
      for (int ni = 0; ni < 4; ++ni)
        acc[mi][ni] = __builtin_amdgcn_mfma_f32_16x16x32_bf16(af[mi], bf8[ni], acc[mi][ni], 0, 0, 0);
  }
  __shared__ float S[64 * 65];
  for (int i = tid; i < 64 * 65; i += 256) S[i] = 0.f;
  __syncthreads();
#pragma unroll
  for (int mi = 0; mi < 4; ++mi)
#pragma unroll
    for (int ni = 0; ni < 4; ++ni)
#pragma unroll
      for (int r = 0; r < 4; ++r)
        atomicAdd(&S[(mi * 16 + quad * 4 + r) * 65 + ni * 16 + l15], acc[mi][ni][r]);
  __syncthreads();
  if (tid < 64) {
    float mx = -1e30f;
    for (int j = 0; j < 64; ++j) mx = fmaxf(mx, S[tid * 65 + j]);
    float sum = 0.f;
    for (int j = 0; j < 64; ++j) sum += __expf((S[tid * 65 + j] - mx) * 0.125f);
    float inv = 1.f / sum;
    float* dst = attn + ((size_t)(bz * NH_ + h) * 64 + tid) * 64;
    for (int j = 0; j < 64; ++j) dst[j] = __expf((S[tid * 65 + j] - mx) * 0.125f) * inv;
  }
}

// ---------------- Kernel 4: O = attn * v  (O written into q region of qkv buffer) -------------
__global__ __launch_bounds__(256) void pv_kernel(const float* __restrict__ attn,
    const u16* __restrict__ qkv, u16* __restrict__ o) {
  int nt = blockIdx.x, h = blockIdx.y, bz = blockIdx.z;
  int n0 = nt * 256;
  const u16* vb = qkv + ((size_t)bz * MQKV + 2 * C_ + h * HD_) * N_;
  __shared__ u16 Ps[64 * 72];
  __shared__ u16 Vs[256 * 72];
  int tid = threadIdx.x, lane = tid & 63, wid = tid >> 6;
  int quad = lane >> 4, l15 = lane & 15;
  const float* ab = attn + (size_t)(bz * NH_ + h) * 4096;
#pragma unroll
  for (int i = 0; i < 16; ++i) {
    int idx = tid + i * 256;
    int row = idx >> 6, col = idx & 63;
    Ps[row * 72 + col] = f2bf(ab[idx]);
  }
#pragma unroll
  for (int i = 0; i < 8; ++i) {
    int l = tid + i * 256;
    int ch = l >> 5, n8 = (l & 31) * 8;
    V16 v; v.u = *(const uintx4*)(vb + (size_t)ch * N_ + n0 + n8);
    int chunk = ch >> 3, clo = ch & 7;
#pragma unroll
    for (int j = 0; j < 8; ++j) {
      int nl = n8 + j;
      Vs[nl * 72 + (chunk ^ ((nl >> 3) & 7)) * 8 + clo] = v.s[j];
    }
  }
  __syncthreads();
  floatx4 acc[4][4];
#pragma unroll
  for (int i = 0; i < 4; ++i)
#pragma unroll
    for (int j = 0; j < 4; ++j) acc[i][j] = (floatx4)0.f;
#pragma unroll
  for (int ks = 0; ks < 2; ++ks) {
    short8 af[4], bf8[4];
    int ko = ks * 32 + quad * 8;
#pragma unroll
    for (int mi = 0; mi < 4; ++mi)
      af[mi] = *(const short8*)&Ps[(mi * 16 + l15) * 72 + ko];
    int chunk = ks * 4 + quad;
#pragma unroll
    for (int ni = 0; ni < 4; ++ni) {
      int nl = wid * 64 + ni * 16 + l15;
      bf8[ni] = *(const short8*)&Vs[nl * 72 + (chunk ^ ((nl >> 3) & 7)) * 8];
    }
#pragma unroll
    for (int mi = 0; mi < 4; ++mi)
#pragma unroll
      for (int ni = 0; ni < 4; ++ni)
        acc[mi][ni] = __builtin_amdgcn_mfma_f32_16x16x32_bf16(af[mi], bf8[ni], acc[mi][ni], 0, 0, 0);
  }
#pragma unroll
  for (int mi = 0; mi < 4; ++mi)
#pragma unroll
    for (int ni = 0; ni < 4; ++ni)
#pragma unroll
      for (int r = 0; r < 4; ++r)
        o[((size_t)bz * MQKV + h * HD_ + mi * 16 + quad * 4 + r) * N_ +
          n0 + wid * 64 + ni * 16 + l15] = f2bf(acc[mi][ni][r]);
}

extern "C" void kernel_launch(void* const* d_in, const int* in_sizes, int n_in,
                              void* d_out, int out_size, void* d_ws, size_t ws_size,
                              hipStream_t stream) {
  const float* x      = (const float*)d_in[0];
  const float* gamma  = (const float*)d_in[1];
  const float* beta   = (const float*)d_in[2];
  const float* w_qkv  = (const float*)d_in[3];
  const float* b_qkv  = (const float*)d_in[4];
  const float* w_proj = (const float*)d_in[5];
  const float* b_proj = (const float*)d_in[6];
  float* out = (float*)d_out;   // reference output dtype is float32

  // ws layout: s_arr[16*512]f32 | t_arr[16*512]f32 | attn[Bc*8*64*64]f32 | qkv[Bc*1536*4096]bf16
  const size_t per_batch = (size_t)NH_ * 64 * 64 * 4 + (size_t)MQKV * N_ * 2;
  int Bc = 16;
  while (Bc > 1 && (size_t)65536 + (size_t)Bc * per_batch > ws_size) Bc >>= 1;

  float* s_arr = (float*)d_ws;                      // [16][512]
  float* t_arr = s_arr + B_ * C_;                   // [16][512]
  float* attn  = t_arr + B_ * C_;                   // [Bc][8][64][64]
  u16* qkv     = (u16*)(attn + (size_t)Bc * NH_ * 64 * 64);  // [Bc][1536][4096]

  gn_stats<<<dim3(B_ * 32), dim3(256), 0, stream>>>(x, gamma, beta, s_arr, t_arr);

  for (int b0 = 0; b0 < B_; b0 += Bc) {
    // QKV GEMM: X = x[b0..b0+Bc) f32, out = qkv bf16 (ws)
    gemm_fused<<<dim3(32, 12, Bc), dim3(256), 0, stream>>>(
        w_qkv, x + (size_t)b0 * C_ * N_, b_qkv, s_arr, t_arr, nullptr, qkv,
        MQKV, 1, 0, 1, 0, (size_t)C_ * N_, b0);
    qk_softmax<<<dim3(NH_, Bc), dim3(256), 0, stream>>>(qkv, attn);
    pv_kernel<<<dim3(16, NH_, Bc), dim3(256), 0, stream>>>(attn, qkv, qkv);
    // proj GEMM: X = attention output (bf16, q region of qkv), +bias +residual(f32 x), out f32
    gemm_fused<<<dim3(32, 4, Bc), dim3(256), 0, stream>>>(
        w_proj, qkv, b_proj, s_arr, t_arr, x + (size_t)b0 * C_ * N_,
        out + (size_t)b0 * C_ * N_, C_, 0, 1, 0, 1, (size_t)MQKV * N_, b0);
  }
}